// Round 6
// baseline (259.153 us; speedup 1.0000x reference)
//
#include <hip/hip_runtime.h>
#include <hip/hip_bf16.h>
#include <math.h>

#define NB 2
#define NN 4096
#define FIN 128
#define FOUT 64
#define LALPHA 0.2f
#define NJC 8             // j-chunks per row (chunk = 512 j = one block)

// ws float-offsets
#define WS_S1   0                           // NB*NN
#define WS_S2   (NB*NN)                     // NB*NN
#define WS_WHT  (2*NB*NN)                   // NB*FOUT*NN ushorts
#define WS_LSL  (2*NB*NN + NB*FOUT*NN/2)    // 256*NJC*32 floats (l partials)
#define WS_SLAB (WS_LSL + 256*NJC*32)       // 256*NJC*2048 floats (acc partials)

typedef __attribute__((ext_vector_type(8))) short short8;
typedef __attribute__((ext_vector_type(4))) float f32x4;

static __device__ inline unsigned int pack2bf(float x, float y) {
    float2 f2; f2.x = x; f2.y = y;
    __hip_bfloat162 pp = __float22bfloat162_rn(f2);
    return *reinterpret_cast<unsigned int*>(&pp);
}

// K1: Wh = h@W ; s1 = Wh@a1 ; s2 = Wh@a2 ; WhT bf16 [b][f][j].
// One wave per (b,row); lane = out feature. Block = 4 waves = 4 consecutive rows.
__global__ __launch_bounds__(256) void k1_proj(const float* __restrict__ h,
                                               const float* __restrict__ W,
                                               const float* __restrict__ a,
                                               float* __restrict__ ws) {
    __shared__ float tbuf[4][68];
    int gid  = blockIdx.x * 256 + threadIdx.x;
    int wid  = gid >> 6;            // 0 .. NB*NN-1
    int lane = threadIdx.x & 63;
    int w    = threadIdx.x >> 6;
    const float* hrow = h + (size_t)wid * FIN;
    float h0 = hrow[lane];
    float h1 = hrow[64 + lane];
    float acc = 0.f;
#pragma unroll
    for (int f = 0; f < 64; ++f) {
        float hf = __shfl(h0, f);
        acc = fmaf(hf, W[f * FOUT + lane], acc);
    }
#pragma unroll
    for (int f = 0; f < 64; ++f) {
        float hf = __shfl(h1, f);
        acc = fmaf(hf, W[(64 + f) * FOUT + lane], acc);
    }
    tbuf[w][lane] = acc;
    float v1 = acc * a[lane];
    float v2 = acc * a[FOUT + lane];
#pragma unroll
    for (int off = 32; off; off >>= 1) {
        v1 += __shfl_xor(v1, off);
        v2 += __shfl_xor(v2, off);
    }
    if (lane == 0) {
        ws[WS_S1 + wid] = v1;
        ws[WS_S2 + wid] = v2;
    }
    __syncthreads();
    // transpose 4 rows x 64 f -> WhT bf16 [b][f][n0..n0+3]
    if (threadIdx.x < 64) {
        int f = threadIdx.x;
        int wid0 = blockIdx.x * 4;
        int b  = wid0 >> 12;         // wid0 / NN
        int n0 = wid0 & (NN - 1);
        unsigned short* whT = (unsigned short*)(ws + WS_WHT);
        uint2 pk;
        pk.x = pack2bf(tbuf[0][f], tbuf[1][f]);
        pk.y = pack2bf(tbuf[2][f], tbuf[3][f]);
        *(uint2*)&whT[(size_t)(b * FOUT + f) * NN + n0] = pk;
    }
}

// K3: fused adj-pack + masked softmax + P@Wh via MFMA.
// Block = 4 waves = 16 rows x 512 j. Pack phase: block reads its 32 KB adj
// slice coalesced (thread t: 32 consecutive ints = 8 independent int4 loads),
// packs to a 1 KB LDS bitmask. Main phase: wave w handles 128 j; A-fragments
// built in registers; bits from LDS. Epilogue: cross-wave LDS atomicAdd
// reduction -> one 2048-float slab slot per block (plain coalesced stores).
// grid = 256 row-tiles x NJC(8) = 2048 blocks -> 8 blocks/CU, 32 waves/CU.
__global__ __launch_bounds__(256, 8) void k3_attn(const int* __restrict__ adj,
                                                  float* __restrict__ ws) {
    __shared__ unsigned int lmask[16][17];   // [row][seg(32j)] +1 pad: conflict-free
    __shared__ float rbuf[2048];             // cross-wave acc reduction
    __shared__ float lbuf[32];               // cross-wave l reduction

    const int tid  = threadIdx.x;
    const int w    = tid >> 6;
    const int lane = tid & 63;
    const int col  = lane & 15;
    const int quad = lane >> 4;
    const int rt   = blockIdx.x >> 3;        // row-tile 0..255
    const int jc   = blockIdx.x & 7;         // j-chunk 0..7
    const int i0   = rt * 16;
    const int jb   = jc * 512;

    // ---- pack phase: 16 rows x 512 j of adj -> bitmask ----
    {
        int row = tid >> 4;                  // 0..15
        int seg = tid & 15;                  // 0..15, 32 j each
        const int* ap = &adj[(size_t)(i0 + row) * NN + jb + seg * 32];
        int4 q[8];
#pragma unroll
        for (int k = 0; k < 8; ++k) q[k] = *(const int4*)(ap + 4 * k);
        const int* vv = (const int*)q;
        unsigned int bits = 0;
#pragma unroll
        for (int b = 0; b < 32; ++b) bits |= (unsigned int)(vv[b] & 1) << b;
        lmask[row][seg] = bits;
    }
    // zero reduction buffers (before the same barrier)
#pragma unroll
    for (int k = 0; k < 8; ++k) rbuf[tid + 256 * k] = 0.f;
    if (tid < 32) lbuf[tid] = 0.f;
    __syncthreads();

    const float* __restrict__ s1 = ws + WS_S1;
    const float* __restrict__ s2 = ws + WS_S2;
    const unsigned short* __restrict__ whT = (const unsigned short*)(ws + WS_WHT);

    unsigned int mw[4];
#pragma unroll
    for (int ks = 0; ks < 4; ++ks) mw[ks] = lmask[col][w * 4 + ks];

    float s1a[2];
#pragma unroll
    for (int b = 0; b < 2; ++b) s1a[b] = s1[b * NN + i0 + col];

    f32x4 acc[2][4];        // [batch][nt]
    float lsum[2] = {0.f, 0.f};
#pragma unroll
    for (int b = 0; b < 2; ++b)
#pragma unroll
        for (int nt = 0; nt < 4; ++nt) acc[b][nt] = (f32x4)0.f;

#pragma unroll
    for (int ks = 0; ks < 4; ++ks) {
        const int j8 = jb + w * 128 + ks * 32 + quad * 8;  // lane's 8-j base
        const unsigned int mbits = mw[ks] >> (quad * 8);
        float4 a0 = *(const float4*)&s2[j8];
        float4 a1 = *(const float4*)&s2[j8 + 4];
        float4 b0 = *(const float4*)&s2[NN + j8];
        float4 b1 = *(const float4*)&s2[NN + j8 + 4];
        float sj0[8] = {a0.x, a0.y, a0.z, a0.w, a1.x, a1.y, a1.z, a1.w};
        float sj1[8] = {b0.x, b0.y, b0.z, b0.w, b1.x, b1.y, b1.z, b1.w};
        float p0[8], p1[8];
#pragma unroll
        for (int jj = 0; jj < 8; ++jj) {
            bool mm = (mbits >> jj) & 1u;              // shared across batches
            float e0 = s1a[0] + sj0[jj];
            e0 = fmaxf(e0, LALPHA * e0);
            p0[jj] = mm ? __expf(e0) : 0.f;
            lsum[0] += p0[jj];
            float e1 = s1a[1] + sj1[jj];
            e1 = fmaxf(e1, LALPHA * e1);
            p1[jj] = mm ? __expf(e1) : 0.f;
            lsum[1] += p1[jj];
        }
        unsigned int k0[4], k1[4];
#pragma unroll
        for (int q = 0; q < 4; ++q) {
            k0[q] = pack2bf(p0[2 * q], p0[2 * q + 1]);
            k1[q] = pack2bf(p1[2 * q], p1[2 * q + 1]);
        }
        short8 af0 = *(short8*)k0;
        short8 af1 = *(short8*)k1;
#pragma unroll
        for (int nt = 0; nt < 4; ++nt) {
            short8 bf0 = *(const short8*)
                &whT[(size_t)(nt * 16 + col) * NN + j8];
            acc[0][nt] = __builtin_amdgcn_mfma_f32_16x16x32_bf16(
                af0, bf0, acc[0][nt], 0, 0, 0);
            short8 bf1 = *(const short8*)
                &whT[(size_t)(FOUT + nt * 16 + col) * NN + j8];
            acc[1][nt] = __builtin_amdgcn_mfma_f32_16x16x32_bf16(
                af1, bf1, acc[1][nt], 0, 0, 0);
        }
    }

    // ---- epilogue: cross-wave LDS reduction, then coalesced slab store ----
#pragma unroll
    for (int b = 0; b < 2; ++b) {
        float v = lsum[b];
        v += __shfl_xor(v, 16);
        v += __shfl_xor(v, 32);
        if (quad == 0) atomicAdd(&lbuf[b * 16 + col], v);
#pragma unroll
        for (int nt = 0; nt < 4; ++nt)
#pragma unroll
            for (int reg = 0; reg < 4; ++reg)
                atomicAdd(&rbuf[(((b * 4 + nt) * 4 + reg) << 6) + lane],
                          acc[b][nt][reg]);
    }
    __syncthreads();
    float* slab = ws + WS_SLAB + (size_t)(rt * NJC + jc) * 2048;
    *(float4*)&slab[tid * 8]     = *(const float4*)&rbuf[tid * 8];
    *(float4*)&slab[tid * 8 + 4] = *(const float4*)&rbuf[tid * 8 + 4];
    if (tid < 32) ws[WS_LSL + (size_t)(rt * NJC + jc) * 32 + tid] = lbuf[tid];
}

// K4: reduce NJC partials, out = elu(acc / l). One thread per output element.
__global__ __launch_bounds__(256) void k4_fin(const float* __restrict__ ws,
                                              float* __restrict__ out) {
    int idx = blockIdx.x * 256 + threadIdx.x;    // (b, row, f) flat
    int f   = idx & 63;
    int row = (idx >> 6) & (NN - 1);
    int b   = idx >> 18;
    int rt  = row >> 4;
    int r16 = row & 15;
    int quad = r16 >> 2, reg = r16 & 3;
    int col  = f & 15,  nt  = f >> 4;
    int lane = quad * 16 + col;
    const float* slab = ws + WS_SLAB + (size_t)rt * NJC * 2048
                        + (((b * 4 + nt) * 4 + reg) << 6) + lane;
    const float* lsl  = ws + WS_LSL + (size_t)rt * NJC * 32 + b * 16 + r16;
    float a = 0.f, l = 0.f;
#pragma unroll
    for (int jc = 0; jc < NJC; ++jc) {
        a += slab[jc * 2048];
        l += lsl[jc * 32];
    }
    float v = a / l;
    out[idx] = v > 0.f ? v : (__expf(v) - 1.f);
}

extern "C" void kernel_launch(void* const* d_in, const int* in_sizes, int n_in,
                              void* d_out, int out_size, void* d_ws, size_t ws_size,
                              hipStream_t stream) {
    const float* h   = (const float*)d_in[0];
    const int*   adj = (const int*)d_in[1];
    const float* W   = (const float*)d_in[2];
    const float* a   = (const float*)d_in[3];
    float* ws  = (float*)d_ws;
    float* out = (float*)d_out;

    hipLaunchKernelGGL(k1_proj, dim3(NB * NN / 4), dim3(256), 0, stream, h, W, a, ws);
    hipLaunchKernelGGL(k3_attn, dim3(256 * NJC),   dim3(256), 0, stream, adj, ws);
    hipLaunchKernelGGL(k4_fin,  dim3(NB * NN * FOUT / 256), dim3(256), 0, stream, ws, out);
}

// Round 7
// 243.603 us; speedup vs baseline: 1.0638x; 1.0638x over previous
//
#include <hip/hip_runtime.h>
#include <hip/hip_bf16.h>
#include <math.h>

#define NB 2
#define NN 4096
#define FIN 128
#define FOUT 64
#define LALPHA 0.2f
#define NJC 8             // j-chunks per row (chunk = 512 j = one block)

// ws float-offsets
#define WS_S1   0                           // NB*NN
#define WS_S2   (NB*NN)                     // NB*NN
#define WS_WHT  (2*NB*NN)                   // NB*FOUT*NN ushorts
#define WS_LSL  (2*NB*NN + NB*FOUT*NN/2)    // 256*NJC*32 floats (l partials)
#define WS_SLAB (WS_LSL + 256*NJC*32)       // 256*NJC*2048 floats (acc partials)

typedef __attribute__((ext_vector_type(8))) short short8;
typedef __attribute__((ext_vector_type(4))) float f32x4;

static __device__ inline unsigned int pack2bf(float x, float y) {
    float2 f2; f2.x = x; f2.y = y;
    __hip_bfloat162 pp = __float22bfloat162_rn(f2);
    return *reinterpret_cast<unsigned int*>(&pp);
}

// K1: Wh = h@W ; s1 = Wh@a1 ; s2 = Wh@a2 ; WhT bf16 [b][f][j].
// One wave per (b,row); lane = out feature. Block = 4 waves = 4 consecutive rows.
__global__ __launch_bounds__(256) void k1_proj(const float* __restrict__ h,
                                               const float* __restrict__ W,
                                               const float* __restrict__ a,
                                               float* __restrict__ ws) {
    __shared__ float tbuf[4][68];
    int gid  = blockIdx.x * 256 + threadIdx.x;
    int wid  = gid >> 6;            // 0 .. NB*NN-1
    int lane = threadIdx.x & 63;
    int w    = threadIdx.x >> 6;
    const float* hrow = h + (size_t)wid * FIN;
    float h0 = hrow[lane];
    float h1 = hrow[64 + lane];
    float acc = 0.f;
#pragma unroll
    for (int f = 0; f < 64; ++f) {
        float hf = __shfl(h0, f);
        acc = fmaf(hf, W[f * FOUT + lane], acc);
    }
#pragma unroll
    for (int f = 0; f < 64; ++f) {
        float hf = __shfl(h1, f);
        acc = fmaf(hf, W[(64 + f) * FOUT + lane], acc);
    }
    tbuf[w][lane] = acc;
    float v1 = acc * a[lane];
    float v2 = acc * a[FOUT + lane];
#pragma unroll
    for (int off = 32; off; off >>= 1) {
        v1 += __shfl_xor(v1, off);
        v2 += __shfl_xor(v2, off);
    }
    if (lane == 0) {
        ws[WS_S1 + wid] = v1;
        ws[WS_S2 + wid] = v2;
    }
    __syncthreads();
    // transpose 4 rows x 64 f -> WhT bf16 [b][f][n0..n0+3]
    if (threadIdx.x < 64) {
        int f = threadIdx.x;
        int wid0 = blockIdx.x * 4;
        int b  = wid0 >> 12;         // wid0 / NN
        int n0 = wid0 & (NN - 1);
        unsigned short* whT = (unsigned short*)(ws + WS_WHT);
        uint2 pk;
        pk.x = pack2bf(tbuf[0][f], tbuf[1][f]);
        pk.y = pack2bf(tbuf[2][f], tbuf[3][f]);
        *(uint2*)&whT[(size_t)(b * FOUT + f) * NN + n0] = pk;
    }
}

// K3: fused adj-pack + masked softmax + P@Wh via MFMA.
// Block = 4 waves = 16 rows x 512 j. Pack phase: block reads its 32 KB adj
// slice (thread t: 32 consecutive ints as 2 rounds of 4 int4 loads), packs to
// a 1 KB LDS bitmask. Main phase: wave w handles 128 j; A-fragments built in
// registers; bits from LDS. Epilogue: cross-wave LDS atomicAdd reduction ->
// one 2048-float slab slot per block (plain coalesced stores).
// __launch_bounds__(256,6): 85 VGPR cap (NO spill -- (256,8)'s 32-VGPR spill
// was R6's 156us regression), 6 blocks/CU, 24 waves/CU. LDS 9.7KB*6 = 58KB.
__global__ __launch_bounds__(256, 6) void k3_attn(const int* __restrict__ adj,
                                                  float* __restrict__ ws) {
    __shared__ unsigned int lmask[16][17];   // [row][seg(32j)] +1 pad: conflict-free
    __shared__ float rbuf[2048];             // cross-wave acc reduction
    __shared__ float lbuf[32];               // cross-wave l reduction

    const int tid  = threadIdx.x;
    const int w    = tid >> 6;
    const int lane = tid & 63;
    const int col  = lane & 15;
    const int quad = lane >> 4;
    const int rt   = blockIdx.x >> 3;        // row-tile 0..255
    const int jc   = blockIdx.x & 7;         // j-chunk 0..7
    const int i0   = rt * 16;
    const int jb   = jc * 512;

    // ---- pack phase: 16 rows x 512 j of adj -> bitmask ----
    {
        int row = tid >> 4;                  // 0..15
        int seg = tid & 15;                  // 0..15, 32 j each
        const int* ap = &adj[(size_t)(i0 + row) * NN + jb + seg * 32];
        unsigned int bits = 0;
#pragma unroll
        for (int half = 0; half < 2; ++half) {
            int4 q[4];
#pragma unroll
            for (int k = 0; k < 4; ++k) q[k] = *(const int4*)(ap + half * 16 + 4 * k);
            const int* vv = (const int*)q;
#pragma unroll
            for (int b = 0; b < 16; ++b)
                bits |= (unsigned int)(vv[b] & 1) << (half * 16 + b);
        }
        lmask[row][seg] = bits;
    }
    // zero reduction buffers (before the same barrier)
#pragma unroll
    for (int k = 0; k < 8; ++k) rbuf[tid + 256 * k] = 0.f;
    if (tid < 32) lbuf[tid] = 0.f;
    __syncthreads();

    const float* __restrict__ s1 = ws + WS_S1;
    const float* __restrict__ s2 = ws + WS_S2;
    const unsigned short* __restrict__ whT = (const unsigned short*)(ws + WS_WHT);

    unsigned int mw[4];
#pragma unroll
    for (int ks = 0; ks < 4; ++ks) mw[ks] = lmask[col][w * 4 + ks];

    float s1a[2];
#pragma unroll
    for (int b = 0; b < 2; ++b) s1a[b] = s1[b * NN + i0 + col];

    f32x4 acc[2][4];        // [batch][nt]
    float lsum[2] = {0.f, 0.f};
#pragma unroll
    for (int b = 0; b < 2; ++b)
#pragma unroll
        for (int nt = 0; nt < 4; ++nt) acc[b][nt] = (f32x4)0.f;

#pragma unroll
    for (int ks = 0; ks < 4; ++ks) {
        const int j8 = jb + w * 128 + ks * 32 + quad * 8;  // lane's 8-j base
        const unsigned int mbits = mw[ks] >> (quad * 8);
        float4 a0 = *(const float4*)&s2[j8];
        float4 a1 = *(const float4*)&s2[j8 + 4];
        float4 b0 = *(const float4*)&s2[NN + j8];
        float4 b1 = *(const float4*)&s2[NN + j8 + 4];
        float sj0[8] = {a0.x, a0.y, a0.z, a0.w, a1.x, a1.y, a1.z, a1.w};
        float sj1[8] = {b0.x, b0.y, b0.z, b0.w, b1.x, b1.y, b1.z, b1.w};
        float p0[8], p1[8];
#pragma unroll
        for (int jj = 0; jj < 8; ++jj) {
            bool mm = (mbits >> jj) & 1u;              // shared across batches
            float e0 = s1a[0] + sj0[jj];
            e0 = fmaxf(e0, LALPHA * e0);
            p0[jj] = mm ? __expf(e0) : 0.f;
            lsum[0] += p0[jj];
            float e1 = s1a[1] + sj1[jj];
            e1 = fmaxf(e1, LALPHA * e1);
            p1[jj] = mm ? __expf(e1) : 0.f;
            lsum[1] += p1[jj];
        }
        unsigned int k0[4], k1[4];
#pragma unroll
        for (int q = 0; q < 4; ++q) {
            k0[q] = pack2bf(p0[2 * q], p0[2 * q + 1]);
            k1[q] = pack2bf(p1[2 * q], p1[2 * q + 1]);
        }
        short8 af0 = *(short8*)k0;
        short8 af1 = *(short8*)k1;
#pragma unroll
        for (int nt = 0; nt < 4; ++nt) {
            short8 bf0 = *(const short8*)
                &whT[(size_t)(nt * 16 + col) * NN + j8];
            acc[0][nt] = __builtin_amdgcn_mfma_f32_16x16x32_bf16(
                af0, bf0, acc[0][nt], 0, 0, 0);
            short8 bf1 = *(const short8*)
                &whT[(size_t)(FOUT + nt * 16 + col) * NN + j8];
            acc[1][nt] = __builtin_amdgcn_mfma_f32_16x16x32_bf16(
                af1, bf1, acc[1][nt], 0, 0, 0);
        }
    }

    // ---- epilogue: cross-wave LDS reduction, then coalesced slab store ----
#pragma unroll
    for (int b = 0; b < 2; ++b) {
        float v = lsum[b];
        v += __shfl_xor(v, 16);
        v += __shfl_xor(v, 32);
        if (quad == 0) atomicAdd(&lbuf[b * 16 + col], v);
#pragma unroll
        for (int nt = 0; nt < 4; ++nt)
#pragma unroll
            for (int reg = 0; reg < 4; ++reg)
                atomicAdd(&rbuf[(((b * 4 + nt) * 4 + reg) << 6) + lane],
                          acc[b][nt][reg]);
    }
    __syncthreads();
    float* slab = ws + WS_SLAB + (size_t)(rt * NJC + jc) * 2048;
    *(float4*)&slab[tid * 8]     = *(const float4*)&rbuf[tid * 8];
    *(float4*)&slab[tid * 8 + 4] = *(const float4*)&rbuf[tid * 8 + 4];
    if (tid < 32) ws[WS_LSL + (size_t)(rt * NJC + jc) * 32 + tid] = lbuf[tid];
}

// K4: reduce NJC partials, out = elu(acc / l). One thread per output element.
__global__ __launch_bounds__(256) void k4_fin(const float* __restrict__ ws,
                                              float* __restrict__ out) {
    int idx = blockIdx.x * 256 + threadIdx.x;    // (b, row, f) flat
    int f   = idx & 63;
    int row = (idx >> 6) & (NN - 1);
    int b   = idx >> 18;
    int rt  = row >> 4;
    int r16 = row & 15;
    int quad = r16 >> 2, reg = r16 & 3;
    int col  = f & 15,  nt  = f >> 4;
    int lane = quad * 16 + col;
    const float* slab = ws + WS_SLAB + (size_t)rt * NJC * 2048
                        + (((b * 4 + nt) * 4 + reg) << 6) + lane;
    const float* lsl  = ws + WS_LSL + (size_t)rt * NJC * 32 + b * 16 + r16;
    float a = 0.f, l = 0.f;
#pragma unroll
    for (int jc = 0; jc < NJC; ++jc) {
        a += slab[jc * 2048];
        l += lsl[jc * 32];
    }
    float v = a / l;
    out[idx] = v > 0.f ? v : (__expf(v) - 1.f);
}

extern "C" void kernel_launch(void* const* d_in, const int* in_sizes, int n_in,
                              void* d_out, int out_size, void* d_ws, size_t ws_size,
                              hipStream_t stream) {
    const float* h   = (const float*)d_in[0];
    const int*   adj = (const int*)d_in[1];
    const float* W   = (const float*)d_in[2];
    const float* a   = (const float*)d_in[3];
    float* ws  = (float*)d_ws;
    float* out = (float*)d_out;

    hipLaunchKernelGGL(k1_proj, dim3(NB * NN / 4), dim3(256), 0, stream, h, W, a, ws);
    hipLaunchKernelGGL(k3_attn, dim3(256 * NJC),   dim3(256), 0, stream, adj, ws);
    hipLaunchKernelGGL(k4_fin,  dim3(NB * NN * FOUT / 256), dim3(256), 0, stream, ws, out);
}

// Round 8
// 181.167 us; speedup vs baseline: 1.4305x; 1.3446x over previous
//
#include <hip/hip_runtime.h>
#include <hip/hip_bf16.h>
#include <math.h>

#define NB 2
#define NN 4096
#define FIN 128
#define FOUT 64
#define LALPHA 0.2f
#define NJC 8             // j-chunks per row (chunk = 512 j = one block)

// ws float-offsets
#define WS_S1   0                           // NB*NN
#define WS_S2   (NB*NN)                     // NB*NN
#define WS_WHT  (2*NB*NN)                   // NB*FOUT*NN ushorts
#define WS_LSL  (2*NB*NN + NB*FOUT*NN/2)    // 256*NJC*32 floats (l partials)
#define WS_SLAB (WS_LSL + 256*NJC*32)       // 256*NJC*2048 floats (acc partials)

typedef __attribute__((ext_vector_type(8))) short short8;
typedef __attribute__((ext_vector_type(4))) float f32x4;

static __device__ inline unsigned int pack2bf(float x, float y) {
    float2 f2; f2.x = x; f2.y = y;
    __hip_bfloat162 pp = __float22bfloat162_rn(f2);
    return *reinterpret_cast<unsigned int*>(&pp);
}

// K1: Wh = h@W ; s1 = Wh@a1 ; s2 = Wh@a2 ; WhT bf16 [b][f][j].
// One wave per (b,row); lane = out feature. Block = 4 waves = 4 consecutive rows.
__global__ __launch_bounds__(256) void k1_proj(const float* __restrict__ h,
                                               const float* __restrict__ W,
                                               const float* __restrict__ a,
                                               float* __restrict__ ws) {
    __shared__ float tbuf[4][68];
    int gid  = blockIdx.x * 256 + threadIdx.x;
    int wid  = gid >> 6;            // 0 .. NB*NN-1
    int lane = threadIdx.x & 63;
    int w    = threadIdx.x >> 6;
    const float* hrow = h + (size_t)wid * FIN;
    float h0 = hrow[lane];
    float h1 = hrow[64 + lane];
    float acc = 0.f;
#pragma unroll
    for (int f = 0; f < 64; ++f) {
        float hf = __shfl(h0, f);
        acc = fmaf(hf, W[f * FOUT + lane], acc);
    }
#pragma unroll
    for (int f = 0; f < 64; ++f) {
        float hf = __shfl(h1, f);
        acc = fmaf(hf, W[(64 + f) * FOUT + lane], acc);
    }
    tbuf[w][lane] = acc;
    float v1 = acc * a[lane];
    float v2 = acc * a[FOUT + lane];
#pragma unroll
    for (int off = 32; off; off >>= 1) {
        v1 += __shfl_xor(v1, off);
        v2 += __shfl_xor(v2, off);
    }
    if (lane == 0) {
        ws[WS_S1 + wid] = v1;
        ws[WS_S2 + wid] = v2;
    }
    __syncthreads();
    // transpose 4 rows x 64 f -> WhT bf16 [b][f][n0..n0+3]
    if (threadIdx.x < 64) {
        int f = threadIdx.x;
        int wid0 = blockIdx.x * 4;
        int b  = wid0 >> 12;         // wid0 / NN
        int n0 = wid0 & (NN - 1);
        unsigned short* whT = (unsigned short*)(ws + WS_WHT);
        uint2 pk;
        pk.x = pack2bf(tbuf[0][f], tbuf[1][f]);
        pk.y = pack2bf(tbuf[2][f], tbuf[3][f]);
        *(uint2*)&whT[(size_t)(b * FOUT + f) * NN + n0] = pk;
    }
}

// K3: fused adj-pack + masked softmax + P@Wh via MFMA.
// Block = 16 rows x 512 j, BOTH batches; wave w = (batch = w>>1, jhalf = w&1)
// covering 256 j of ONE batch -> per-wave regs ~40 arch + 16 AGPR acc (fits
// (256,6)'s 85-cap with NO spill; R6/R7's dual-batch waves spilled: 32/40
// arch VGPRs, WRITE_SIZE 133/53 MB scratch).
// Pack phase: block reads its 32 KB adj slice coalesced -> 1 KB LDS bitmask
// (shared by both batches); s2 slice staged to LDS. Main loop: A-fragment in
// registers, mask + s2 from LDS (broadcast, conflict-free), whT B-frags from
// L2. Epilogue: LDS reduction -> one coalesced 2048-float slab slot per block.
__global__ __launch_bounds__(256, 6) void k3_attn(const int* __restrict__ adj,
                                                  float* __restrict__ ws) {
    __shared__ unsigned int lmask[16][17];   // [row][seg(32j)], 2-way max: free
    __shared__ float sbuf[2][512];           // s2 slice, both batches
    __shared__ float rbuf[2048];             // cross-wave acc reduction
    __shared__ float lbuf[32];               // cross-wave l reduction

    const int tid  = threadIdx.x;
    const int w    = tid >> 6;
    const int lane = tid & 63;
    const int col  = lane & 15;
    const int quad = lane >> 4;
    const int bw   = w >> 1;                 // wave's batch
    const int jh   = w & 1;                  // wave's j-half
    const int rt   = blockIdx.x >> 3;        // row-tile 0..255
    const int jc   = blockIdx.x & 7;         // j-chunk 0..7
    const int i0   = rt * 16;
    const int jb   = jc * 512;

    // ---- pack phase: 16 rows x 512 j of adj -> bitmask ----
    {
        int row = tid >> 4;                  // 0..15
        int seg = tid & 15;                  // 0..15, 32 j each
        const int* ap = &adj[(size_t)(i0 + row) * NN + jb + seg * 32];
        unsigned int bits = 0;
#pragma unroll
        for (int half = 0; half < 2; ++half) {
            int4 q[4];
#pragma unroll
            for (int k = 0; k < 4; ++k) q[k] = *(const int4*)(ap + half * 16 + 4 * k);
            const int* vv = (const int*)q;
#pragma unroll
            for (int t = 0; t < 16; ++t)
                bits |= (unsigned int)(vv[t] & 1) << (half * 16 + t);
        }
        lmask[row][seg] = bits;
    }
    // ---- stage s2 slice (both batches, 512 j, 4 KB) ----
    {
        int bb  = tid >> 7;                  // 0..1
        int off = (tid & 127) * 4;
        *(float4*)&sbuf[bb][off] = *(const float4*)&(ws + WS_S2)[bb * NN + jb + off];
    }
    // zero reduction buffers (before the same barrier)
#pragma unroll
    for (int k = 0; k < 8; ++k) rbuf[tid + 256 * k] = 0.f;
    if (tid < 32) lbuf[tid] = 0.f;
    __syncthreads();

    const unsigned short* __restrict__ whT = (const unsigned short*)(ws + WS_WHT);
    const float s1v = (ws + WS_S1)[bw * NN + i0 + col];

    f32x4 acc[4];
    float lsum = 0.f;
#pragma unroll
    for (int nt = 0; nt < 4; ++nt) acc[nt] = (f32x4)0.f;

#pragma unroll
    for (int ks = 0; ks < 8; ++ks) {
        const int jo = jh * 256 + ks * 32 + quad * 8;   // LDS j-offset
        const int j8 = jb + jo;                         // global j
        const unsigned int mbits = lmask[col][jh * 8 + ks] >> (quad * 8);
        float4 a0 = *(const float4*)&sbuf[bw][jo];
        float4 a1 = *(const float4*)&sbuf[bw][jo + 4];
        float sj[8] = {a0.x, a0.y, a0.z, a0.w, a1.x, a1.y, a1.z, a1.w};
        float p[8];
#pragma unroll
        for (int jj = 0; jj < 8; ++jj) {
            bool mm = (mbits >> jj) & 1u;
            float e = s1v + sj[jj];
            e = fmaxf(e, LALPHA * e);          // leakyrelu
            p[jj] = mm ? __expf(e) : 0.f;      // mask
            lsum += p[jj];
        }
        unsigned int pk[4];
#pragma unroll
        for (int q = 0; q < 4; ++q) pk[q] = pack2bf(p[2 * q], p[2 * q + 1]);
        short8 afrag = *(short8*)pk;
#pragma unroll
        for (int nt = 0; nt < 4; ++nt) {
            short8 bfrag = *(const short8*)
                &whT[(size_t)(bw * FOUT + nt * 16 + col) * NN + j8];
            acc[nt] = __builtin_amdgcn_mfma_f32_16x16x32_bf16(
                afrag, bfrag, acc[nt], 0, 0, 0);
        }
    }

    // ---- epilogue: cross-wave LDS reduction, then coalesced slab store ----
    {
        float v = lsum;
        v += __shfl_xor(v, 16);
        v += __shfl_xor(v, 32);
        if (quad == 0) atomicAdd(&lbuf[bw * 16 + col], v);
#pragma unroll
        for (int nt = 0; nt < 4; ++nt)
#pragma unroll
            for (int reg = 0; reg < 4; ++reg)
                atomicAdd(&rbuf[(((bw * 4 + nt) * 4 + reg) << 6) + lane],
                          acc[nt][reg]);
    }
    __syncthreads();
    float* slab = ws + WS_SLAB + (size_t)(rt * NJC + jc) * 2048;
    *(float4*)&slab[tid * 8]     = *(const float4*)&rbuf[tid * 8];
    *(float4*)&slab[tid * 8 + 4] = *(const float4*)&rbuf[tid * 8 + 4];
    if (tid < 32) ws[WS_LSL + (size_t)(rt * NJC + jc) * 32 + tid] = lbuf[tid];
}

// K4: reduce NJC partials, out = elu(acc / l). One thread per output element.
__global__ __launch_bounds__(256) void k4_fin(const float* __restrict__ ws,
                                              float* __restrict__ out) {
    int idx = blockIdx.x * 256 + threadIdx.x;    // (b, row, f) flat
    int f   = idx & 63;
    int row = (idx >> 6) & (NN - 1);
    int b   = idx >> 18;
    int rt  = row >> 4;
    int r16 = row & 15;
    int quad = r16 >> 2, reg = r16 & 3;
    int col  = f & 15,  nt  = f >> 4;
    int lane = quad * 16 + col;
    const float* slab = ws + WS_SLAB + (size_t)rt * NJC * 2048
                        + (((b * 4 + nt) * 4 + reg) << 6) + lane;
    const float* lsl  = ws + WS_LSL + (size_t)rt * NJC * 32 + b * 16 + r16;
    float a = 0.f, l = 0.f;
#pragma unroll
    for (int jc = 0; jc < NJC; ++jc) {
        a += slab[jc * 2048];
        l += lsl[jc * 32];
    }
    float v = a / l;
    out[idx] = v > 0.f ? v : (__expf(v) - 1.f);
}

extern "C" void kernel_launch(void* const* d_in, const int* in_sizes, int n_in,
                              void* d_out, int out_size, void* d_ws, size_t ws_size,
                              hipStream_t stream) {
    const float* h   = (const float*)d_in[0];
    const int*   adj = (const int*)d_in[1];
    const float* W   = (const float*)d_in[2];
    const float* a   = (const float*)d_in[3];
    float* ws  = (float*)d_ws;
    float* out = (float*)d_out;

    hipLaunchKernelGGL(k1_proj, dim3(NB * NN / 4), dim3(256), 0, stream, h, W, a, ws);
    hipLaunchKernelGGL(k3_attn, dim3(256 * NJC),   dim3(256), 0, stream, adj, ws);
    hipLaunchKernelGGL(k4_fin,  dim3(NB * NN * FOUT / 256), dim3(256), 0, stream, ws, out);
}

// Round 9
// 175.071 us; speedup vs baseline: 1.4803x; 1.0348x over previous
//
#include <hip/hip_runtime.h>
#include <hip/hip_bf16.h>
#include <math.h>

#define NB 2
#define NN 4096
#define NNP 4128          // padded whT row stride: 8256 B, breaks L2 channel camping
#define FIN 128
#define FOUT 64
#define LALPHA 0.2f
#define NJC 8             // j-chunks per row (chunk = 512 j = one block)

// ws float-offsets
#define WS_S1   0                           // NB*NN
#define WS_S2   (NB*NN)                     // NB*NN
#define WS_WHT  (2*NB*NN)                   // NB*FOUT*NNP ushorts
#define WS_LSL  (2*NB*NN + NB*FOUT*NNP/2)   // 256*NJC*32 floats (l partials)
#define WS_SLAB (WS_LSL + 256*NJC*32)       // 256*NJC*2048 floats (acc partials)

typedef __attribute__((ext_vector_type(8))) short short8;
typedef __attribute__((ext_vector_type(4))) float f32x4;

static __device__ inline unsigned int pack2bf(float x, float y) {
    float2 f2; f2.x = x; f2.y = y;
    __hip_bfloat162 pp = __float22bfloat162_rn(f2);
    return *reinterpret_cast<unsigned int*>(&pp);
}

// K1: Wh = h@W ; s1 = Wh@a1 ; s2 = Wh@a2 ; WhT bf16 [b][f][j] (stride NNP).
// One wave per (b,row); lane = out feature. Block = 4 waves = 4 consecutive rows.
__global__ __launch_bounds__(256) void k1_proj(const float* __restrict__ h,
                                               const float* __restrict__ W,
                                               const float* __restrict__ a,
                                               float* __restrict__ ws) {
    __shared__ float tbuf[4][68];
    int gid  = blockIdx.x * 256 + threadIdx.x;
    int wid  = gid >> 6;            // 0 .. NB*NN-1
    int lane = threadIdx.x & 63;
    int w    = threadIdx.x >> 6;
    const float* hrow = h + (size_t)wid * FIN;
    float h0 = hrow[lane];
    float h1 = hrow[64 + lane];
    float acc = 0.f;
#pragma unroll
    for (int f = 0; f < 64; ++f) {
        float hf = __shfl(h0, f);
        acc = fmaf(hf, W[f * FOUT + lane], acc);
    }
#pragma unroll
    for (int f = 0; f < 64; ++f) {
        float hf = __shfl(h1, f);
        acc = fmaf(hf, W[(64 + f) * FOUT + lane], acc);
    }
    tbuf[w][lane] = acc;
    float v1 = acc * a[lane];
    float v2 = acc * a[FOUT + lane];
#pragma unroll
    for (int off = 32; off; off >>= 1) {
        v1 += __shfl_xor(v1, off);
        v2 += __shfl_xor(v2, off);
    }
    if (lane == 0) {
        ws[WS_S1 + wid] = v1;
        ws[WS_S2 + wid] = v2;
    }
    __syncthreads();
    // transpose 4 rows x 64 f -> WhT bf16 [b][f][n0..n0+3]
    if (threadIdx.x < 64) {
        int f = threadIdx.x;
        int wid0 = blockIdx.x * 4;
        int b  = wid0 >> 12;         // wid0 / NN
        int n0 = wid0 & (NN - 1);
        unsigned short* whT = (unsigned short*)(ws + WS_WHT);
        uint2 pk;
        pk.x = pack2bf(tbuf[0][f], tbuf[1][f]);
        pk.y = pack2bf(tbuf[2][f], tbuf[3][f]);
        *(uint2*)&whT[(size_t)(b * FOUT + f) * NNP + n0] = pk;
    }
}

// K3: fused adj-pack + masked softmax + P@Wh via MFMA.
// Block = 16 rows x 512 j, BOTH batches; wave w = (batch = w>>1, jhalf = w&1)
// covering 256 j of ONE batch. Pack phase: block reads its 32 KB adj slice
// coalesced -> 1 KB LDS bitmask (shared by both batches); s2 slice staged to
// LDS. Main loop: A-fragment in registers, mask + s2 from LDS (broadcast,
// conflict-free), whT B-frags from L2 at PADDED stride (NNP) -- R8's 8192 B
// power-of-2 stride put all 16 col-lanes' lines on ONE L2 channel (16x
// serialization on the hottest load; VALUBusy 16%, all pipes idle).
// Epilogue: LDS reduction -> one coalesced 2048-float slab slot per block.
__global__ __launch_bounds__(256, 6) void k3_attn(const int* __restrict__ adj,
                                                  float* __restrict__ ws) {
    __shared__ unsigned int lmask[16][17];   // [row][seg(32j)], conflict-free
    __shared__ float sbuf[2][512];           // s2 slice, both batches
    __shared__ float rbuf[2048];             // cross-wave acc reduction
    __shared__ float lbuf[32];               // cross-wave l reduction

    const int tid  = threadIdx.x;
    const int w    = tid >> 6;
    const int lane = tid & 63;
    const int col  = lane & 15;
    const int quad = lane >> 4;
    const int bw   = w >> 1;                 // wave's batch
    const int jh   = w & 1;                  // wave's j-half
    const int rt   = blockIdx.x >> 3;        // row-tile 0..255
    const int jc   = blockIdx.x & 7;         // j-chunk 0..7
    const int i0   = rt * 16;
    const int jb   = jc * 512;

    // ---- pack phase: 16 rows x 512 j of adj -> bitmask ----
    {
        int row = tid >> 4;                  // 0..15
        int seg = tid & 15;                  // 0..15, 32 j each
        const int* ap = &adj[(size_t)(i0 + row) * NN + jb + seg * 32];
        unsigned int bits = 0;
#pragma unroll
        for (int half = 0; half < 2; ++half) {
            int4 q[4];
#pragma unroll
            for (int k = 0; k < 4; ++k) q[k] = *(const int4*)(ap + half * 16 + 4 * k);
            const int* vv = (const int*)q;
#pragma unroll
            for (int t = 0; t < 16; ++t)
                bits |= (unsigned int)(vv[t] & 1) << (half * 16 + t);
        }
        lmask[row][seg] = bits;
    }
    // ---- stage s2 slice (both batches, 512 j, 4 KB) ----
    {
        int bb  = tid >> 7;                  // 0..1
        int off = (tid & 127) * 4;
        *(float4*)&sbuf[bb][off] = *(const float4*)&(ws + WS_S2)[bb * NN + jb + off];
    }
    // zero reduction buffers (before the same barrier)
#pragma unroll
    for (int k = 0; k < 8; ++k) rbuf[tid + 256 * k] = 0.f;
    if (tid < 32) lbuf[tid] = 0.f;
    __syncthreads();

    const unsigned short* __restrict__ whT = (const unsigned short*)(ws + WS_WHT);
    const float s1v = (ws + WS_S1)[bw * NN + i0 + col];

    f32x4 acc[4];
    float lsum = 0.f;
#pragma unroll
    for (int nt = 0; nt < 4; ++nt) acc[nt] = (f32x4)0.f;

#pragma unroll
    for (int ks = 0; ks < 8; ++ks) {
        const int jo = jh * 256 + ks * 32 + quad * 8;   // LDS j-offset
        const int j8 = jb + jo;                         // global j
        const unsigned int mbits = lmask[col][jh * 8 + ks] >> (quad * 8);
        float4 a0 = *(const float4*)&sbuf[bw][jo];
        float4 a1 = *(const float4*)&sbuf[bw][jo + 4];
        float sj[8] = {a0.x, a0.y, a0.z, a0.w, a1.x, a1.y, a1.z, a1.w};
        float p[8];
#pragma unroll
        for (int jj = 0; jj < 8; ++jj) {
            bool mm = (mbits >> jj) & 1u;
            float e = s1v + sj[jj];
            e = fmaxf(e, LALPHA * e);          // leakyrelu
            p[jj] = mm ? __expf(e) : 0.f;      // mask
            lsum += p[jj];
        }
        unsigned int pk[4];
#pragma unroll
        for (int q = 0; q < 4; ++q) pk[q] = pack2bf(p[2 * q], p[2 * q + 1]);
        short8 afrag = *(short8*)pk;
#pragma unroll
        for (int nt = 0; nt < 4; ++nt) {
            short8 bfrag = *(const short8*)
                &whT[(size_t)(bw * FOUT + nt * 16 + col) * NNP + j8];
            acc[nt] = __builtin_amdgcn_mfma_f32_16x16x32_bf16(
                afrag, bfrag, acc[nt], 0, 0, 0);
        }
    }

    // ---- epilogue: cross-wave LDS reduction, then coalesced slab store ----
    {
        float v = lsum;
        v += __shfl_xor(v, 16);
        v += __shfl_xor(v, 32);
        if (quad == 0) atomicAdd(&lbuf[bw * 16 + col], v);
#pragma unroll
        for (int nt = 0; nt < 4; ++nt)
#pragma unroll
            for (int reg = 0; reg < 4; ++reg)
                atomicAdd(&rbuf[(((bw * 4 + nt) * 4 + reg) << 6) + lane],
                          acc[nt][reg]);
    }
    __syncthreads();
    float* slab = ws + WS_SLAB + (size_t)(rt * NJC + jc) * 2048;
    *(float4*)&slab[tid * 8]     = *(const float4*)&rbuf[tid * 8];
    *(float4*)&slab[tid * 8 + 4] = *(const float4*)&rbuf[tid * 8 + 4];
    if (tid < 32) ws[WS_LSL + (size_t)(rt * NJC + jc) * 32 + tid] = lbuf[tid];
}

// K4: reduce NJC partials, out = elu(acc / l). One thread per output element.
__global__ __launch_bounds__(256) void k4_fin(const float* __restrict__ ws,
                                              float* __restrict__ out) {
    int idx = blockIdx.x * 256 + threadIdx.x;    // (b, row, f) flat
    int f   = idx & 63;
    int row = (idx >> 6) & (NN - 1);
    int b   = idx >> 18;
    int rt  = row >> 4;
    int r16 = row & 15;
    int quad = r16 >> 2, reg = r16 & 3;
    int col  = f & 15,  nt  = f >> 4;
    int lane = quad * 16 + col;
    const float* slab = ws + WS_SLAB + (size_t)rt * NJC * 2048
                        + (((b * 4 + nt) * 4 + reg) << 6) + lane;
    const float* lsl  = ws + WS_LSL + (size_t)rt * NJC * 32 + b * 16 + r16;
    float a = 0.f, l = 0.f;
#pragma unroll
    for (int jc = 0; jc < NJC; ++jc) {
        a += slab[jc * 2048];
        l += lsl[jc * 32];
    }
    float v = a / l;
    out[idx] = v > 0.f ? v : (__expf(v) - 1.f);
}

extern "C" void kernel_launch(void* const* d_in, const int* in_sizes, int n_in,
                              void* d_out, int out_size, void* d_ws, size_t ws_size,
                              hipStream_t stream) {
    const float* h   = (const float*)d_in[0];
    const int*   adj = (const int*)d_in[1];
    const float* W   = (const float*)d_in[2];
    const float* a   = (const float*)d_in[3];
    float* ws  = (float*)d_ws;
    float* out = (float*)d_out;

    hipLaunchKernelGGL(k1_proj, dim3(NB * NN / 4), dim3(256), 0, stream, h, W, a, ws);
    hipLaunchKernelGGL(k3_attn, dim3(256 * NJC),   dim3(256), 0, stream, adj, ws);
    hipLaunchKernelGGL(k4_fin,  dim3(NB * NN * FOUT / 256), dim3(256), 0, stream, ws, out);
}